// Round 3
// baseline (309.908 us; speedup 1.0000x reference)
//
#include <hip/hip_runtime.h>
#include <hip/hip_bf16.h>
#include <math.h>

// Problem constants
#define NODES   65536
#define DD      128
#define BM      64          // nodes per block: X tile = 64 KB -> 2 blocks/CU
#define NSUB    24          // 384 N-rows / 16 per subtile
#define WTILE_STRIDE (NSUB * 64 * 8)      // 12288 shorts per W k-tile
#define WG_STRIDE    (20 * WTILE_STRIDE)  // 16 Wih + 4 Whh k-tiles per GRU

typedef __bf16 bf16x8 __attribute__((ext_vector_type(8)));
typedef float  f32x4  __attribute__((ext_vector_type(4)));

static __device__ __forceinline__ float fastcos(float x) {
    float r = x * 0.15915494309189535f;                   // x / (2*pi)
    r = r - floorf(r);                                    // range-reduce to [0,1)
    return __builtin_amdgcn_cosf(r);                      // v_cos_f32 (revolutions)
}
static __device__ __forceinline__ float fsigmoid(float x) {
    return 1.0f / (1.0f + __expf(-x));
}
static __device__ __forceinline__ float ftanh(float x) {
    float ax = fabsf(x);
    float t  = __expf(-2.0f * ax);
    float th = 1.0f - 2.0f * t / (1.0f + t);
    return copysignf(th, x);
}
// pack 4 floats -> 4 bf16 (RNE) in one uint2 via 2x v_cvt_pk_bf16_f32
static __device__ __forceinline__ uint2 cvtpk4(float4 v) {
    uint2 r;
    asm("v_cvt_pk_bf16_f32 %0, %1, %2" : "=v"(r.x) : "v"(v.x), "v"(v.y));
    asm("v_cvt_pk_bf16_f32 %0, %1, %2" : "=v"(r.y) : "v"(v.z), "v"(v.w));
    return r;
}
static __device__ __forceinline__ unsigned short f2bf(float f) {
    union { float f; unsigned u; } v; v.f = f;
    return (unsigned short)((v.u + 0x8000u) >> 16);
}

// ---------------------------------------------------------------------------
// Kernel 1: pre-swizzle W into per-lane MFMA B-fragment order (bf16) in ws.
// (unchanged — layout is BM-independent)
// ---------------------------------------------------------------------------
__global__ void prep_w_kernel(const float* __restrict__ Wih0, const float* __restrict__ Whh0,
                              const float* __restrict__ Wih1, const float* __restrict__ Whh1,
                              unsigned short* __restrict__ Wws) {
    int gid = blockIdx.x * 256 + threadIdx.x;
    if (gid >= 2 * WG_STRIDE) return;
    int g   = gid / WG_STRIDE;
    int r   = gid - g * WG_STRIDE;
    int kt  = r / WTILE_STRIDE;
    int r2  = r - kt * WTILE_STRIDE;
    int t   = r2 >> 9;                 // subtile 0..23
    int l8  = r2 & 511;
    int lane = l8 >> 3, j = l8 & 7;
    int cl  = lane & 15, q = lane >> 4;
    int n   = t * 16 + cl;
    const float* Wih = g ? Wih1 : Wih0;
    const float* Whh = g ? Whh1 : Whh0;
    float v;
    if (kt < 16) v = Wih[n * 512 + kt * 32 + q * 8 + j];
    else         v = Whh[n * 128 + (kt - 16) * 32 + q * 8 + j];
    Wws[gid] = f2bf(v);
}

// ---------------------------------------------------------------------------
// Kernel 2: BM=64, 8 waves, 2 blocks/CU. X rows XOR-swizzled (byte^=(row&7)<<4).
// Staging: per instruction a wave covers 2 rows x one contiguous 256-B segment
// window (conflict-free banks). T14: oth gather issued pre-barrier-1, written
// after the 8 h/Whh tiles; feat gather hidden under the 4 te tiles.
// ---------------------------------------------------------------------------

// One K-tile: A from X col st*32, B triple from k-tile kt, N-gate acc slot sn.
#define KTILE(st, kt, sn)                                                      \
    do {                                                                       \
        bf16x8 a[4];                                                           \
        _Pragma("unroll")                                                      \
        for (int j = 0; j < 4; ++j)                                            \
            a[j] = *(const bf16x8*)(Xb + (j * 16 + cl) * 1024 +                \
                                    (((st) * 64 + q * 16) ^ swz));             \
        const unsigned short* wk = wbase + (size_t)(kt) * WTILE_STRIDE;        \
        bf16x8 bR = *(const bf16x8*)(wk + tR * 512);                           \
        bf16x8 bZ = *(const bf16x8*)(wk + tZ * 512);                           \
        bf16x8 bN = *(const bf16x8*)(wk + tN * 512);                           \
        _Pragma("unroll")                                                      \
        for (int j = 0; j < 4; ++j) {                                          \
            acc[j * 4 + 0]  = __builtin_amdgcn_mfma_f32_16x16x32_bf16(a[j], bR, acc[j * 4 + 0], 0, 0, 0);  \
            acc[j * 4 + 1]  = __builtin_amdgcn_mfma_f32_16x16x32_bf16(a[j], bZ, acc[j * 4 + 1], 0, 0, 0);  \
            acc[j * 4 + sn] = __builtin_amdgcn_mfma_f32_16x16x32_bf16(a[j], bN, acc[j * 4 + sn], 0, 0, 0); \
        }                                                                      \
    } while (0)

__global__ __launch_bounds__(512, 4) void tgn_fused_kernel(
    const int*   __restrict__ n_id,
    const float* __restrict__ memory_,
    const float* __restrict__ pos_mem,
    const float* __restrict__ pos_emb,
    const float* __restrict__ raw_s,
    const float* __restrict__ raw_d,
    const int*   __restrict__ other_s,
    const int*   __restrict__ other_d,
    const int*   __restrict__ t_s,
    const int*   __restrict__ t_d,
    const int*   __restrict__ last_update,
    const float* __restrict__ w_time_mem, const float* __restrict__ b_time_mem,
    const float* __restrict__ w_time_pos, const float* __restrict__ b_time_pos,
    const float* __restrict__ bih_mem, const float* __restrict__ bhh_mem,
    const float* __restrict__ bih_pos, const float* __restrict__ bhh_pos,
    const unsigned short* __restrict__ Wws,
    float* __restrict__ out)
{
    __shared__ __align__(16) unsigned short X[BM * 512];   // 65536 B, swizzled
    __shared__ int   snid[BM];
    __shared__ int   soth[BM];
    __shared__ float sdt[BM];
    __shared__ int   sfeat[BM];

    const int g   = blockIdx.y;
    const int nb  = blockIdx.x;
    const int tid = threadIdx.x;
    const int lane = tid & 63;
    const int wv   = tid >> 6;

    const float* mem_g = g ? pos_mem    : memory_;
    const float* wt    = g ? w_time_pos : w_time_mem;
    const float* bt    = g ? b_time_pos : b_time_mem;
    const float* bih   = g ? bih_pos    : bih_mem;
    const float* bhh   = g ? bhh_pos    : bhh_mem;

    // ---- phase 0: per-node scalars ----
    if (tid < BM) {
        int gi   = nb * BM + tid;
        int id   = n_id[gi];
        int ts   = t_s[gi];
        int td   = t_d[gi];
        bool pick = (ts >= td);
        int oth  = pick ? other_s[gi] : other_d[gi];
        int lu   = last_update[id];
        float dt = (float)(pick ? ts : td) - (float)lu;
        int code;
        if (g) code = pick ? id : other_d[gi];          // row into pos_emb
        else   code = pick ? gi : ~gi;                  // >=0: raw_s row, <0: raw_d row ~code
        snid[tid]  = id;
        soth[tid]  = oth;
        sdt[tid]   = dt;
        sfeat[tid] = code;
        if (g == 0) {
            out[2 * (size_t)NODES * DD + gi] = (float)max(ts, td);   // last_up as fp32
        }
    }
    __syncthreads();

    // ---- staging geometry: wave owns rows [wv*8, wv*8+8); per instruction
    // 2 rows (lane>>5) x 32 lanes spanning one contiguous 256-B segment ----
    const int lc    = lane & 31;            // column lane within row
    const int rh    = lane >> 5;            // row half
    const int srow0 = wv * 8;

    // ---- issue oth gather FIRST (longest latency: random HBM) ----
    float4 of[4];
    #pragma unroll
    for (int c = 0; c < 4; ++c) {
        int row = srow0 + 2 * c + rh;
        of[c] = *(const float4*)(mem_g + (size_t)soth[row] * DD + lc * 4);
    }
    __builtin_amdgcn_sched_barrier(0);

    // ---- stage h (sequential rows, coalesced) ----
    #pragma unroll
    for (int c = 0; c < 4; ++c) {
        int row = srow0 + 2 * c + rh;
        float4 v = *(const float4*)(mem_g + (size_t)snid[row] * DD + lc * 4);
        *(uint2*)((char*)X + row * 1024 + ((lc * 8) ^ ((row & 7) << 4))) = cvtpk4(v);
    }
    // ---- stage te (VALU: fastcos) ----
    #pragma unroll
    for (int c = 0; c < 4; ++c) {
        int row = srow0 + 2 * c + rh;
        float dt = sdt[row];
        float4 wv4 = *(const float4*)(wt + lc * 4);
        float4 bv4 = *(const float4*)(bt + lc * 4);
        float4 tv;
        tv.x = fastcos(dt * wv4.x + bv4.x);
        tv.y = fastcos(dt * wv4.y + bv4.y);
        tv.z = fastcos(dt * wv4.z + bv4.z);
        tv.w = fastcos(dt * wv4.w + bv4.w);
        *(uint2*)((char*)X + row * 1024 + ((768 + lc * 8) ^ ((row & 7) << 4))) = cvtpk4(tv);
    }
    __syncthreads();   // barrier 1: h + te visible (oth loads still in flight)

    // ---- K-loop state ----
    f32x4 acc[16];     // [j(m-tile 0..3)][slot 0=r,1=z,2=inn,3=hn]
    #pragma unroll
    for (int i = 0; i < 16; ++i) acc[i] = (f32x4){0.f, 0.f, 0.f, 0.f};

    const int q  = lane >> 4;
    const int cl = lane & 15;
    const int swz = (cl & 7) << 4;
    const unsigned short* wbase = Wws + (size_t)g * WG_STRIDE + lane * 8;
    const int tR = wv, tZ = 8 + wv, tN = 16 + wv;
    const char* Xb = (const char*)X;

    // ---- K part 1a: h cols, Wih (slot 2) + Whh (slot 3) ----
    __builtin_amdgcn_s_setprio(1);
    KTILE(0, 0, 2);  KTILE(0, 16, 3);
    KTILE(1, 1, 2);  KTILE(1, 17, 3);
    KTILE(2, 2, 2);  KTILE(2, 18, 3);
    KTILE(3, 3, 2);  KTILE(3, 19, 3);
    __builtin_amdgcn_s_setprio(0);

    // ---- write oth to LDS (waits on the gather; conflict-free window) ----
    #pragma unroll
    for (int c = 0; c < 4; ++c) {
        int row = srow0 + 2 * c + rh;
        *(uint2*)((char*)X + row * 1024 + ((256 + lc * 8) ^ ((row & 7) << 4))) = cvtpk4(of[c]);
    }

    // ---- issue feat gather (hides under the 4 te tiles) ----
    float4 ff[4];
    #pragma unroll
    for (int c = 0; c < 4; ++c) {
        int row = srow0 + 2 * c + rh;
        const float* src;
        if (g) {
            src = pos_emb + (size_t)sfeat[row] * DD;
        } else {
            int code = sfeat[row];
            src = code >= 0 ? raw_s + (size_t)code * DD
                            : raw_d + (size_t)(~code) * DD;
        }
        ff[c] = *(const float4*)(src + lc * 4);
    }
    __builtin_amdgcn_sched_barrier(0);

    // ---- K part 1b: te cols ----
    __builtin_amdgcn_s_setprio(1);
    KTILE(12, 12, 2); KTILE(13, 13, 2); KTILE(14, 14, 2); KTILE(15, 15, 2);
    __builtin_amdgcn_s_setprio(0);

    // ---- write feat to LDS ----
    #pragma unroll
    for (int c = 0; c < 4; ++c) {
        int row = srow0 + 2 * c + rh;
        *(uint2*)((char*)X + row * 1024 + ((512 + lc * 8) ^ ((row & 7) << 4))) = cvtpk4(ff[c]);
    }
    __syncthreads();   // barrier 2: oth + feat visible

    // ---- K part 2: oth + feat cols ----
    __builtin_amdgcn_s_setprio(1);
    KTILE(4, 4, 2);   KTILE(5, 5, 2);   KTILE(6, 6, 2);   KTILE(7, 7, 2);
    KTILE(8, 8, 2);   KTILE(9, 9, 2);   KTILE(10, 10, 2); KTILE(11, 11, 2);
    __builtin_amdgcn_s_setprio(0);

    // ---- GRU epilogue, in-lane. C/D: col(n)=lane&15, row(m)=q*4+reg ----
    float* outz = out + (size_t)g * NODES * DD;
    const int d = wv * 16 + cl;
    float br  = bih[d]       + bhh[d];
    float bz  = bih[128 + d] + bhh[128 + d];
    float bni = bih[256 + d];
    float bnh = bhh[256 + d];
    #pragma unroll
    for (int j = 0; j < 4; ++j) {
        #pragma unroll
        for (int r = 0; r < 4; ++r) {
            int il = j * 16 + q * 4 + r;                 // node row in block
            float rs  = acc[j * 4 + 0][r] + br;
            float zs  = acc[j * 4 + 1][r] + bz;
            float in_ = acc[j * 4 + 2][r] + bni;
            float hn_ = acc[j * 4 + 3][r] + bnh;
            float rg = fsigmoid(rs);
            float zg = fsigmoid(zs);
            float nv = ftanh(in_ + rg * hn_);
            float h  = mem_g[(size_t)snid[il] * DD + d];
            outz[(size_t)(nb * BM + il) * DD + d] = (1.0f - zg) * nv + zg * h;
        }
    }
}

// ---------------------------------------------------------------------------
extern "C" void kernel_launch(void* const* d_in, const int* in_sizes, int n_in,
                              void* d_out, int out_size, void* d_ws, size_t ws_size,
                              hipStream_t stream) {
    const int*   n_id        = (const int*)  d_in[0];
    const float* memory_     = (const float*)d_in[1];
    const float* pos_mem     = (const float*)d_in[2];
    const float* pos_emb     = (const float*)d_in[3];
    const float* raw_s       = (const float*)d_in[4];
    const float* raw_d       = (const float*)d_in[5];
    const int*   other_s     = (const int*)  d_in[6];
    const int*   other_d     = (const int*)  d_in[7];
    const int*   t_s         = (const int*)  d_in[8];
    const int*   t_d         = (const int*)  d_in[9];
    const int*   last_update = (const int*)  d_in[10];
    const float* w_time_mem  = (const float*)d_in[11];
    const float* b_time_mem  = (const float*)d_in[12];
    const float* w_time_pos  = (const float*)d_in[13];
    const float* b_time_pos  = (const float*)d_in[14];
    const float* Wih_mem     = (const float*)d_in[15];
    const float* Whh_mem     = (const float*)d_in[16];
    const float* bih_mem     = (const float*)d_in[17];
    const float* bhh_mem     = (const float*)d_in[18];
    const float* Wih_pos     = (const float*)d_in[19];
    const float* Whh_pos     = (const float*)d_in[20];
    const float* bih_pos     = (const float*)d_in[21];
    const float* bhh_pos     = (const float*)d_in[22];

    unsigned short* Wws = (unsigned short*)d_ws;   // 2*245760 bf16 = 983 KB
    float* out = (float*)d_out;

    prep_w_kernel<<<(2 * WG_STRIDE + 255) / 256, 256, 0, stream>>>(
        Wih_mem, Whh_mem, Wih_pos, Whh_pos, Wws);

    dim3 grid(NODES / BM, 2);
    tgn_fused_kernel<<<grid, 512, 0, stream>>>(
        n_id, memory_, pos_mem, pos_emb, raw_s, raw_d,
        other_s, other_d, t_s, t_d, last_update,
        w_time_mem, b_time_mem, w_time_pos, b_time_pos,
        bih_mem, bhh_mem, bih_pos, bhh_pos,
        Wws, out);
}

// Round 4
// 285.308 us; speedup vs baseline: 1.0862x; 1.0862x over previous
//
#include <hip/hip_runtime.h>
#include <hip/hip_bf16.h>
#include <math.h>

// Problem constants
#define NODES   65536
#define DD      128
#define BM      64          // nodes per block: X tile = 64 KB -> 2 blocks/CU
#define NSUB    24          // 384 N-rows / 16 per subtile
#define WTILE_STRIDE (NSUB * 64 * 8)      // 12288 shorts per W k-tile
#define WG_STRIDE    (20 * WTILE_STRIDE)  // 16 Wih + 4 Whh k-tiles per GRU

typedef __bf16 bf16x8 __attribute__((ext_vector_type(8)));
typedef float  f32x4  __attribute__((ext_vector_type(4)));

static __device__ __forceinline__ unsigned short f2bf(float f) {
    union { float f; unsigned u; } v; v.f = f;
    return (unsigned short)((v.u + 0x8000u) >> 16);      // round-half-up bf16
}
static __device__ __forceinline__ ushort4 pack4(float4 v) {
    ushort4 p;
    p.x = f2bf(v.x); p.y = f2bf(v.y); p.z = f2bf(v.z); p.w = f2bf(v.w);
    return p;
}
static __device__ __forceinline__ float fastcos(float x) {
    float r = x * 0.15915494309189535f;                   // x / (2*pi)
    r = r - floorf(r);                                    // range-reduce to [0,1)
    return __builtin_amdgcn_cosf(r);                      // v_cos_f32 (revolutions)
}
static __device__ __forceinline__ float fsigmoid(float x) {
    return 1.0f / (1.0f + __expf(-x));
}
static __device__ __forceinline__ float ftanh(float x) {
    float ax = fabsf(x);
    float t  = __expf(-2.0f * ax);
    float th = 1.0f - 2.0f * t / (1.0f + t);
    return copysignf(th, x);
}

// ---------------------------------------------------------------------------
// Kernel 1: pre-swizzle W into per-lane MFMA B-fragment order (bf16) in ws.
// ---------------------------------------------------------------------------
__global__ void prep_w_kernel(const float* __restrict__ Wih0, const float* __restrict__ Whh0,
                              const float* __restrict__ Wih1, const float* __restrict__ Whh1,
                              unsigned short* __restrict__ Wws) {
    int gid = blockIdx.x * 256 + threadIdx.x;
    if (gid >= 2 * WG_STRIDE) return;
    int g   = gid / WG_STRIDE;
    int r   = gid - g * WG_STRIDE;
    int kt  = r / WTILE_STRIDE;
    int r2  = r - kt * WTILE_STRIDE;
    int t   = r2 >> 9;                 // subtile 0..23
    int l8  = r2 & 511;
    int lane = l8 >> 3, j = l8 & 7;
    int cl  = lane & 15, q = lane >> 4;
    int n   = t * 16 + cl;
    const float* Wih = g ? Wih1 : Wih0;
    const float* Whh = g ? Whh1 : Whh0;
    float v;
    if (kt < 16) v = Wih[n * 512 + kt * 32 + q * 8 + j];
    else         v = Whh[n * 128 + (kt - 16) * 32 + q * 8 + j];
    Wws[gid] = f2bf(v);
}

// ---------------------------------------------------------------------------
// Kernel 2: BM=64, 8 waves, 2 blocks/CU. X rows XOR-swizzled (byte^=(row&7)<<4).
// 2-phase: ALL staging streams in flight simultaneously, issued in consumption
// order (vmcnt is in-order: never consume a younger load before an older one
// you want to stay outstanding). All gather regs die before acc is born.
// ---------------------------------------------------------------------------

// K-tile, Wih only: A from X col st*32, B triple from k-tile st.
#define KTILE(st)                                                              \
    do {                                                                       \
        bf16x8 a[4];                                                           \
        _Pragma("unroll")                                                      \
        for (int j = 0; j < 4; ++j)                                            \
            a[j] = *(const bf16x8*)(Xb + (j * 16 + cl) * 1024 +                \
                                    (((st) * 64 + q * 16) ^ swz));             \
        const unsigned short* wk = wbase + (size_t)(st) * WTILE_STRIDE;        \
        bf16x8 bR = *(const bf16x8*)(wk + tR * 512);                           \
        bf16x8 bZ = *(const bf16x8*)(wk + tZ * 512);                           \
        bf16x8 bN = *(const bf16x8*)(wk + tN * 512);                           \
        _Pragma("unroll")                                                      \
        for (int j = 0; j < 4; ++j) {                                          \
            acc[j * 4 + 0] = __builtin_amdgcn_mfma_f32_16x16x32_bf16(a[j], bR, acc[j * 4 + 0], 0, 0, 0); \
            acc[j * 4 + 1] = __builtin_amdgcn_mfma_f32_16x16x32_bf16(a[j], bZ, acc[j * 4 + 1], 0, 0, 0); \
            acc[j * 4 + 2] = __builtin_amdgcn_mfma_f32_16x16x32_bf16(a[j], bN, acc[j * 4 + 2], 0, 0, 0); \
        }                                                                      \
    } while (0)

// K-tile on h cols: Wih k-tile st AND Whh k-tile 16+st share the A-frags.
#define KTILE2(st)                                                             \
    do {                                                                       \
        bf16x8 a[4];                                                           \
        _Pragma("unroll")                                                      \
        for (int j = 0; j < 4; ++j)                                            \
            a[j] = *(const bf16x8*)(Xb + (j * 16 + cl) * 1024 +                \
                                    (((st) * 64 + q * 16) ^ swz));             \
        const unsigned short* wk = wbase + (size_t)(st) * WTILE_STRIDE;        \
        const unsigned short* wh = wbase + (size_t)(16 + (st)) * WTILE_STRIDE; \
        bf16x8 bR = *(const bf16x8*)(wk + tR * 512);                           \
        bf16x8 bZ = *(const bf16x8*)(wk + tZ * 512);                           \
        bf16x8 bN = *(const bf16x8*)(wk + tN * 512);                           \
        bf16x8 cR = *(const bf16x8*)(wh + tR * 512);                           \
        bf16x8 cZ = *(const bf16x8*)(wh + tZ * 512);                           \
        bf16x8 cN = *(const bf16x8*)(wh + tN * 512);                           \
        _Pragma("unroll")                                                      \
        for (int j = 0; j < 4; ++j) {                                          \
            acc[j * 4 + 0] = __builtin_amdgcn_mfma_f32_16x16x32_bf16(a[j], bR, acc[j * 4 + 0], 0, 0, 0); \
            acc[j * 4 + 1] = __builtin_amdgcn_mfma_f32_16x16x32_bf16(a[j], bZ, acc[j * 4 + 1], 0, 0, 0); \
            acc[j * 4 + 2] = __builtin_amdgcn_mfma_f32_16x16x32_bf16(a[j], bN, acc[j * 4 + 2], 0, 0, 0); \
            acc[j * 4 + 0] = __builtin_amdgcn_mfma_f32_16x16x32_bf16(a[j], cR, acc[j * 4 + 0], 0, 0, 0); \
            acc[j * 4 + 1] = __builtin_amdgcn_mfma_f32_16x16x32_bf16(a[j], cZ, acc[j * 4 + 1], 0, 0, 0); \
            acc[j * 4 + 3] = __builtin_amdgcn_mfma_f32_16x16x32_bf16(a[j], cN, acc[j * 4 + 3], 0, 0, 0); \
        }                                                                      \
    } while (0)

__global__ __launch_bounds__(512, 4) void tgn_fused_kernel(
    const int*   __restrict__ n_id,
    const float* __restrict__ memory_,
    const float* __restrict__ pos_mem,
    const float* __restrict__ pos_emb,
    const float* __restrict__ raw_s,
    const float* __restrict__ raw_d,
    const int*   __restrict__ other_s,
    const int*   __restrict__ other_d,
    const int*   __restrict__ t_s,
    const int*   __restrict__ t_d,
    const int*   __restrict__ last_update,
    const float* __restrict__ w_time_mem, const float* __restrict__ b_time_mem,
    const float* __restrict__ w_time_pos, const float* __restrict__ b_time_pos,
    const float* __restrict__ bih_mem, const float* __restrict__ bhh_mem,
    const float* __restrict__ bih_pos, const float* __restrict__ bhh_pos,
    const unsigned short* __restrict__ Wws,
    float* __restrict__ out)
{
    __shared__ __align__(16) unsigned short X[BM * 512];   // 65536 B, swizzled
    __shared__ int   snid[BM];
    __shared__ int   soth[BM];
    __shared__ float sdt[BM];
    __shared__ int   sfeat[BM];

    const int g   = blockIdx.y;
    const int nb  = blockIdx.x;
    const int tid = threadIdx.x;
    const int lane = tid & 63;
    const int wv   = tid >> 6;

    const float* mem_g = g ? pos_mem    : memory_;
    const float* wt    = g ? w_time_pos : w_time_mem;
    const float* bt    = g ? b_time_pos : b_time_mem;
    const float* bih   = g ? bih_pos    : bih_mem;
    const float* bhh   = g ? bhh_pos    : bhh_mem;

    // ---- phase 0: per-node scalars ----
    if (tid < BM) {
        int gi   = nb * BM + tid;
        int id   = n_id[gi];
        int ts   = t_s[gi];
        int td   = t_d[gi];
        bool pick = (ts >= td);
        int oth  = pick ? other_s[gi] : other_d[gi];
        int lu   = last_update[id];
        float dt = (float)(pick ? ts : td) - (float)lu;
        int code;
        if (g) code = pick ? id : other_d[gi];          // row into pos_emb
        else   code = pick ? gi : ~gi;                  // >=0: raw_s row, <0: raw_d row ~code
        snid[tid]  = id;
        soth[tid]  = oth;
        sdt[tid]   = dt;
        sfeat[tid] = code;
        if (g == 0) {
            out[2 * (size_t)NODES * DD + gi] = (float)max(ts, td);   // last_up as fp32
        }
    }
    __syncthreads();

    // ---- staging geometry: wave owns rows [wv*8, wv*8+8); per chunk c the
    // wave covers rows srow0+2c+{0,1}, 32 lanes x 8 B contiguous per row ----
    const int lc    = lane & 31;            // column lane within row
    const int rh    = lane >> 5;            // row half
    const int srow0 = wv * 8;

    // ---- issue ALL streams, oldest = consumed first ----
    // (1) wt/bt: consumed first (te VALU)
    float4 wv4 = *(const float4*)(wt + lc * 4);
    float4 bv4 = *(const float4*)(bt + lc * 4);
    __builtin_amdgcn_sched_barrier(0);
    // (2) h: sequential rows, consumed second
    float4 hv[4];
    #pragma unroll
    for (int c = 0; c < 4; ++c) {
        int row = srow0 + 2 * c + rh;
        hv[c] = *(const float4*)(mem_g + (size_t)snid[row] * DD + lc * 4);
    }
    __builtin_amdgcn_sched_barrier(0);
    // (3) oth: random gather, consumed third (stays in flight under te+h)
    float4 of[4];
    #pragma unroll
    for (int c = 0; c < 4; ++c) {
        int row = srow0 + 2 * c + rh;
        of[c] = *(const float4*)(mem_g + (size_t)soth[row] * DD + lc * 4);
    }
    __builtin_amdgcn_sched_barrier(0);

    // ---- te: pure VALU on wt/bt (h/of/ff still outstanding) ----
    #pragma unroll
    for (int c = 0; c < 4; ++c) {
        int row = srow0 + 2 * c + rh;
        float dt = sdt[row];
        float4 tv;
        tv.x = fastcos(dt * wv4.x + bv4.x);
        tv.y = fastcos(dt * wv4.y + bv4.y);
        tv.z = fastcos(dt * wv4.z + bv4.z);
        tv.w = fastcos(dt * wv4.w + bv4.w);
        *(ushort4*)((char*)X + row * 1024 + ((768 + lc * 8) ^ ((row & 7) << 4))) = pack4(tv);
    }
    // ---- h convert+write (waits h only; of newer, stays outstanding) ----
    #pragma unroll
    for (int c = 0; c < 4; ++c) {
        int row = srow0 + 2 * c + rh;
        *(ushort4*)((char*)X + row * 1024 + ((lc * 8) ^ ((row & 7) << 4))) = pack4(hv[c]);
    }
    // ---- issue feat gather now (h regs just died; of older stays ordered) ----
    float4 ff[4];
    #pragma unroll
    for (int c = 0; c < 4; ++c) {
        int row = srow0 + 2 * c + rh;
        const float* src;
        if (g) {
            src = pos_emb + (size_t)sfeat[row] * DD;
        } else {
            int code = sfeat[row];
            src = code >= 0 ? raw_s + (size_t)code * DD
                            : raw_d + (size_t)(~code) * DD;
        }
        ff[c] = *(const float4*)(src + lc * 4);
    }
    __builtin_amdgcn_sched_barrier(0);
    // ---- oth write (waits of; ff newer, stays outstanding) ----
    #pragma unroll
    for (int c = 0; c < 4; ++c) {
        int row = srow0 + 2 * c + rh;
        *(ushort4*)((char*)X + row * 1024 + ((256 + lc * 8) ^ ((row & 7) << 4))) = pack4(of[c]);
    }
    // ---- feat write ----
    #pragma unroll
    for (int c = 0; c < 4; ++c) {
        int row = srow0 + 2 * c + rh;
        *(ushort4*)((char*)X + row * 1024 + ((512 + lc * 8) ^ ((row & 7) << 4))) = pack4(ff[c]);
    }
    __syncthreads();   // the ONLY barrier before the K-loop; all gather regs dead

    // ---- K-loop state (acc born AFTER all staging regs died -> no spill) ----
    f32x4 acc[16];     // [j(m-tile 0..3)][slot 0=r,1=z,2=inn,3=hn]
    #pragma unroll
    for (int i = 0; i < 16; ++i) acc[i] = (f32x4){0.f, 0.f, 0.f, 0.f};

    const int q  = lane >> 4;
    const int cl = lane & 15;
    const int swz = (cl & 7) << 4;
    const unsigned short* wbase = Wws + (size_t)g * WG_STRIDE + lane * 8;
    const int tR = wv, tZ = 8 + wv, tN = 16 + wv;
    const char* Xb = (const char*)X;

    __builtin_amdgcn_s_setprio(1);
    KTILE2(0); KTILE2(1); KTILE2(2); KTILE2(3);      // h cols: Wih + Whh fused
    KTILE(4);  KTILE(5);  KTILE(6);  KTILE(7);       // oth cols
    KTILE(8);  KTILE(9);  KTILE(10); KTILE(11);      // feat cols
    KTILE(12); KTILE(13); KTILE(14); KTILE(15);      // te cols
    __builtin_amdgcn_s_setprio(0);

    // ---- GRU epilogue, in-lane. C/D: col(n)=lane&15, row(m)=q*4+reg ----
    float* outz = out + (size_t)g * NODES * DD;
    const int d = wv * 16 + cl;
    float br  = bih[d]       + bhh[d];
    float bz  = bih[128 + d] + bhh[128 + d];
    float bni = bih[256 + d];
    float bnh = bhh[256 + d];
    #pragma unroll
    for (int j = 0; j < 4; ++j) {
        #pragma unroll
        for (int r = 0; r < 4; ++r) {
            int il = j * 16 + q * 4 + r;                 // node row in block
            float rs  = acc[j * 4 + 0][r] + br;
            float zs  = acc[j * 4 + 1][r] + bz;
            float in_ = acc[j * 4 + 2][r] + bni;
            float hn_ = acc[j * 4 + 3][r] + bnh;
            float rg = fsigmoid(rs);
            float zg = fsigmoid(zs);
            float nv = ftanh(in_ + rg * hn_);
            float h  = mem_g[(size_t)snid[il] * DD + d];
            outz[(size_t)(nb * BM + il) * DD + d] = (1.0f - zg) * nv + zg * h;
        }
    }
}

// ---------------------------------------------------------------------------
extern "C" void kernel_launch(void* const* d_in, const int* in_sizes, int n_in,
                              void* d_out, int out_size, void* d_ws, size_t ws_size,
                              hipStream_t stream) {
    const int*   n_id        = (const int*)  d_in[0];
    const float* memory_     = (const float*)d_in[1];
    const float* pos_mem     = (const float*)d_in[2];
    const float* pos_emb     = (const float*)d_in[3];
    const float* raw_s       = (const float*)d_in[4];
    const float* raw_d       = (const float*)d_in[5];
    const int*   other_s     = (const int*)  d_in[6];
    const int*   other_d     = (const int*)  d_in[7];
    const int*   t_s         = (const int*)  d_in[8];
    const int*   t_d         = (const int*)  d_in[9];
    const int*   last_update = (const int*)  d_in[10];
    const float* w_time_mem  = (const float*)d_in[11];
    const float* b_time_mem  = (const float*)d_in[12];
    const float* w_time_pos  = (const float*)d_in[13];
    const float* b_time_pos  = (const float*)d_in[14];
    const float* Wih_mem     = (const float*)d_in[15];
    const float* Whh_mem     = (const float*)d_in[16];
    const float* bih_mem     = (const float*)d_in[17];
    const float* bhh_mem     = (const float*)d_in[18];
    const float* Wih_pos     = (const float*)d_in[19];
    const float* Whh_pos     = (const float*)d_in[20];
    const float* bih_pos     = (const float*)d_in[21];
    const float* bhh_pos     = (const float*)d_in[22];

    unsigned short* Wws = (unsigned short*)d_ws;   // 2*245760 bf16 = 983 KB
    float* out = (float*)d_out;

    prep_w_kernel<<<(2 * WG_STRIDE + 255) / 256, 256, 0, stream>>>(
        Wih_mem, Whh_mem, Wih_pos, Whh_pos, Wws);

    dim3 grid(NODES / BM, 2);
    tgn_fused_kernel<<<grid, 512, 0, stream>>>(
        n_id, memory_, pos_mem, pos_emb, raw_s, raw_d,
        other_s, other_d, t_s, t_d, last_update,
        w_time_mem, b_time_mem, w_time_pos, b_time_pos,
        bih_mem, bhh_mem, bih_pos, bhh_pos,
        Wws, out);
}